// Round 22
// baseline (1108.679 us; speedup 1.0000x reference)
//
#include <hip/hip_runtime.h>

// Problem constants (B=2, N=8192, C=64, K=32 neighbors). All device buffers fp32.
static constexpr int gB = 2;
static constexpr int gN = 8192;
static constexpr int gC = 64;
static constexpr int gK = 32;

using u16 = unsigned short;
using u32 = unsigned int;
using u64 = unsigned long long;

// wave(64)-wide sum
__device__ __forceinline__ float wsum(float v) {
#pragma unroll
    for (int m = 32; m; m >>= 1) v += __shfl_xor(v, m, 64);
    return v;
}

// bf16 pack/unpack (RNE)
__device__ __forceinline__ u16 f2bf(float f) {
    u32 u = __float_as_uint(f);
    return (u16)((u + 0x7FFFu + ((u >> 16) & 1u)) >> 16);
}
__device__ __forceinline__ float bf2f(u16 v) {
    return __uint_as_float(((u32)v) << 16);
}

// =====================================================================
// A: fn = LN1(features); Q/K/V = fn@W+b.  Wave-per-point.
// R22: k_pack fused in (lane 0 per wave writes {x,y,z,sq}, contract-off
// scope keeps pack bits identical to the passing k_pack).
// Block 0 also zeroes the meanb accumulator region.
// =====================================================================
__global__ __launch_bounds__(256) void k_lnqkv(
    const float* __restrict__ feat, const float* __restrict__ ln1g, const float* __restrict__ ln1b,
    const float* __restrict__ Wq, const float* __restrict__ bq,
    const float* __restrict__ Wk, const float* __restrict__ bk,
    const float* __restrict__ Wv, const float* __restrict__ bv,
    float* __restrict__ Qo, float* __restrict__ Ko, float* __restrict__ Vo,
    float* __restrict__ zero_region,
    const float* __restrict__ xyz, float4* __restrict__ pk4)
{
    if (blockIdx.x == 0) zero_region[threadIdx.x] = 0.f;   // meanb(128)+pad(128)
    int wave = threadIdx.x >> 6, lane = threadIdx.x & 63;
    int p = blockIdx.x * 4 + wave;
    if (lane == 0) {
#pragma clang fp contract(off)
        const float* s = xyz + (size_t)p * 3;
        float x = s[0], y = s[1], z = s[2];
        float nn = sqrtf((x * x + y * y) + z * z);
        pk4[p] = make_float4(x, y, z, nn * nn);            // norm-then-square
    }
    float x = feat[(size_t)p * gC + lane];
    float mu = wsum(x) * (1.f / 64);
    float d = x - mu;
    float var = wsum(d * d) * (1.f / 64);
    float inv = 1.f / sqrtf(var + 1e-5f);
    float fn = d * inv * ln1g[lane] + ln1b[lane];
    float qa = bq[lane], ka = bk[lane], va = bv[lane];
    for (int cp = 0; cp < 64; ++cp) {
        float hv = __shfl(fn, cp, 64);
        qa += hv * Wq[cp * 64 + lane];
        ka += hv * Wk[cp * 64 + lane];
        va += hv * Wv[cp * 64 + lane];
    }
    size_t o = (size_t)p * gC + lane;
    Qo[o] = qa; Ko[o] = ka; Vo[o] = va;
}

// =====================================================================
// B: KNN top-32 — block = 4 queries, cooperative LDS tiles. R22: u32
// fast-path threshold compare (khmin); full u64 compare only on the
// rare candidate-insert path. Semantics identical (ties -> u64 path).
// =====================================================================
__global__ __launch_bounds__(256) void k_knn(const float4* __restrict__ pk4, int* __restrict__ idxo)
{
#pragma clang fp contract(off)
    __shared__ float xs[1024], ys[1024], zs[1024], ws[1024];   // 16 KB
    int tid = threadIdx.x;
    int wave = tid >> 6, lane = tid & 63;
    int q = blockIdx.x * 4 + wave;            // 4 queries per block, same batch
    int b = q >> 13;
    int n = q & (gN - 1);
    const float4* base = pk4 + (size_t)b * gN;
    float4 me = base[n];
    float xi = me.x, yi = me.y, zi = me.z;
    float sqi = me.w;
    u64 lst[10];
#pragma unroll
    for (int e = 0; e < 10; ++e) lst[e] = 0ull;
    u32 khmin = 0u;

    for (int tile = 0; tile < 8; ++tile) {
        __syncthreads();
#pragma unroll
        for (int t0 = 0; t0 < 4; ++t0) {
            int t = tid + (t0 << 8);
            float4 c = base[(tile << 10) + t];
            xs[t] = c.x; ys[t] = c.y; zs[t] = c.z; ws[t] = c.w;
        }
        __syncthreads();
#pragma unroll 4
        for (int i = 0; i < 16; ++i) {
            int t = (i << 6) | lane;
            float inner = (xi * xs[t] + yi * ys[t]) + zi * zs[t];
            float nd = -((sqi - 2.0f * inner) + ws[t]);
            u32 u = __float_as_uint(nd);
            u32 kh = u ^ (0x80000000u | (u32)((int)u >> 31));   // order-preserving
            if (kh >= khmin) {                                   // fast-path filter
                int j = (tile << 10) + t;
                u64 pk = ((u64)kh << 32) | (u32)(8191 - j);      // ties -> smaller j
                if (pk > lst[9]) {
                    lst[9] = pk;
#pragma unroll
                    for (int e = 9; e > 0; --e) {
                        if (lst[e] > lst[e - 1]) { u64 tm = lst[e - 1]; lst[e - 1] = lst[e]; lst[e] = tm; }
                    }
                    khmin = (u32)(lst[9] >> 32);
                }
            }
        }
    }
    // per-wave extraction
    int* op = idxo + (size_t)q * gK;
    for (int r = 0; r < gK; ++r) {
        u64 g = lst[0];
#pragma unroll
        for (int m = 32; m; m >>= 1) {
            u64 o = __shfl_xor(g, m, 64);
            g = (o > g) ? o : g;
        }
        if (lst[0] == g) {                        // unique owner pops
#pragma unroll
            for (int e = 0; e < 9; ++e) lst[e] = lst[e + 1];
            lst[9] = 0ull;
        }
        if (lane == 0) op[r] = 8191 - (int)(g & 0x1FFFu);
    }
}

// =====================================================================
// C: wave-per-POINT, lane=channel, k-in-registers. (unchanged from R19-21:
// VGPR=100 no-spill, VALUBusy 71%)
// =====================================================================
__global__ __launch_bounds__(256, 2) void k_attn(
    const float* __restrict__ xyz,
    const float* __restrict__ Qb, const float* __restrict__ Kb, const float* __restrict__ Vb,
    const int* __restrict__ idxi,
    const float* __restrict__ dW1, const float* __restrict__ db1,
    const float* __restrict__ dgv, const float* __restrict__ dbv,
    const float* __restrict__ dW2, const float* __restrict__ db2,
    const float* __restrict__ gW1, const float* __restrict__ gb1,
    const float* __restrict__ ggv, const float* __restrict__ gbv,
    const float* __restrict__ gW2, const float* __restrict__ gb2,
    float* __restrict__ att)
{
    __shared__ u16 wd2s[64 * 64];          // 8 KB each: [c][swizzled cp]
    __shared__ u16 wg1s[64 * 64];
    __shared__ u16 wg2s[64 * 64];
    __shared__ float hbuf[4][32][64];      // 32 KB: per-wave activations [k][c]
    __shared__ u16 pebuf[4][32][64];       // 16 KB: per-wave pe (bf16)
    __shared__ float4 dxb[4][32];          // 2 KB
    __shared__ int jb[4][32];              // 0.5 KB

    int tid = threadIdx.x;
    int w = tid >> 6, lane = tid & 63;
    int p = blockIdx.x * 4 + w;
    int b = p >> 13;

    // ---- stage weights: bf16, transposed ([c][cp]), b64-granule swizzle ----
    for (int i = tid; i < 4096; i += 256) {
        int cp = i >> 6, c = i & 63;
        int di = c * 64 + ((((cp >> 2) ^ (c & 15)) << 2) | (cp & 3));
        wd2s[di] = f2bf(dW2[i]);
        wg1s[di] = f2bf(gW1[i]);
        wg2s[di] = f2bf(gW2[i]);
    }
    // ---- stage neighbor indices + pos diffs ----
    if (lane < 32) {
        int j = idxi[(size_t)p * gK + lane];
        jb[w][lane] = j;
        const float* xp = xyz + (size_t)p * 3;
        const float* xj = xyz + ((size_t)b * gN + j) * 3;
        dxb[w][lane] = make_float4(xp[0] - xj[0], xp[1] - xj[1], xp[2] - xj[2], 0.f);
    }
    __syncthreads();

    // per-lane (channel) parameters
    float w1x = dW1[lane], w1y = dW1[64 + lane], w1z = dW1[128 + lane], vb1 = db1[lane];
    float vdg = dgv[lane], vdb = dbv[lane];
    float vb2 = db2[lane];
    float vg1b = gb1[lane], vgg = ggv[lane], vgb = gbv[lane], vg2b = gb2[lane];
    float q = Qb[(size_t)p * gC + lane];

    // ---- fc_delta layer 1 + LN + relu -> hbuf ----
#pragma unroll
    for (int kk = 0; kk < 32; ++kk) {
        float4 d4 = dxb[w][kk];
        float t = d4.x * w1x + d4.y * w1y + d4.z * w1z + vb1;
        float mu = wsum(t) * (1.f / 64);
        float td = t - mu;
        float var = wsum(td * td) * (1.f / 64);
        float inv = 1.f / sqrtf(var + 1e-5f);
        hbuf[w][kk][lane] = fmaxf(td * inv * vdg + vdb, 0.f);
    }

    float acc[32];

    // ---- fc_delta layer 2: pe = h @ dW2 + db2 ----
#pragma unroll
    for (int kk = 0; kk < 32; ++kk) acc[kk] = vb2;
    for (int cp4 = 0; cp4 < 16; ++cp4) {
        int pg = cp4 ^ (lane & 15);
        uint2 wp = *reinterpret_cast<const uint2*>(&wd2s[lane * 64 + pg * 4]);
        float w0 = bf2f((u16)(wp.x & 0xFFFFu)), w1 = bf2f((u16)(wp.x >> 16));
        float w2 = bf2f((u16)(wp.y & 0xFFFFu)), w3 = bf2f((u16)(wp.y >> 16));
#pragma unroll
        for (int kk = 0; kk < 32; ++kk) {
            float4 h4 = *reinterpret_cast<const float4*>(&hbuf[w][kk][cp4 * 4]);
            acc[kk] += h4.x * w0 + h4.y * w1 + h4.z * w2 + h4.w * w3;
        }
    }
#pragma unroll
    for (int kk = 0; kk < 32; ++kk) pebuf[w][kk][lane] = f2bf(acc[kk]);

    // ---- attn_in = (q - k) + pe -> hbuf ----
    {
        const float* Kbb = Kb + (size_t)b * gN * gC;
#pragma unroll
        for (int kk = 0; kk < 32; ++kk) {
            float kv = Kbb[(size_t)jb[w][kk] * gC + lane];
            hbuf[w][kk][lane] = (q - kv) + acc[kk];
        }
    }

    // ---- fc_gamma layer 1 ----
#pragma unroll
    for (int kk = 0; kk < 32; ++kk) acc[kk] = vg1b;
    for (int cp4 = 0; cp4 < 16; ++cp4) {
        int pg = cp4 ^ (lane & 15);
        uint2 wp = *reinterpret_cast<const uint2*>(&wg1s[lane * 64 + pg * 4]);
        float w0 = bf2f((u16)(wp.x & 0xFFFFu)), w1 = bf2f((u16)(wp.x >> 16));
        float w2 = bf2f((u16)(wp.y & 0xFFFFu)), w3 = bf2f((u16)(wp.y >> 16));
#pragma unroll
        for (int kk = 0; kk < 32; ++kk) {
            float4 h4 = *reinterpret_cast<const float4*>(&hbuf[w][kk][cp4 * 4]);
            acc[kk] += h4.x * w0 + h4.y * w1 + h4.z * w2 + h4.w * w3;
        }
    }
    // ---- LN + relu -> hbuf ----
#pragma unroll
    for (int kk = 0; kk < 32; ++kk) {
        float a = acc[kk];
        float mu = wsum(a) * (1.f / 64);
        float ad = a - mu;
        float var = wsum(ad * ad) * (1.f / 64);
        float inv = 1.f / sqrtf(var + 1e-5f);
        hbuf[w][kk][lane] = fmaxf(ad * inv * vgg + vgb, 0.f);
    }

    // ---- fc_gamma layer 2 -> logits ----
#pragma unroll
    for (int kk = 0; kk < 32; ++kk) acc[kk] = vg2b;
    for (int cp4 = 0; cp4 < 16; ++cp4) {
        int pg = cp4 ^ (lane & 15);
        uint2 wp = *reinterpret_cast<const uint2*>(&wg2s[lane * 64 + pg * 4]);
        float w0 = bf2f((u16)(wp.x & 0xFFFFu)), w1 = bf2f((u16)(wp.x >> 16));
        float w2 = bf2f((u16)(wp.y & 0xFFFFu)), w3 = bf2f((u16)(wp.y >> 16));
#pragma unroll
        for (int kk = 0; kk < 32; ++kk) {
            float4 h4 = *reinterpret_cast<const float4*>(&hbuf[w][kk][cp4 * 4]);
            acc[kk] += h4.x * w0 + h4.y * w1 + h4.z * w2 + h4.w * w3;
        }
    }

    // ---- softmax over k (in-lane) + out = sum a*(v+pe) ----
#pragma unroll
    for (int kk = 0; kk < 32; ++kk) acc[kk] *= 0.3535533905932738f;   // /sqrt(8)
    float mx = acc[0];
#pragma unroll
    for (int kk = 1; kk < 32; ++kk) mx = fmaxf(mx, acc[kk]);
    float s = 0.f;
#pragma unroll
    for (int kk = 0; kk < 32; ++kk) { acc[kk] = expf(acc[kk] - mx); s += acc[kk]; }
    {
        const float* Vbb = Vb + (size_t)b * gN * gC;
        float o = 0.f;
#pragma unroll
        for (int kk = 0; kk < 32; ++kk) {
            float vv = Vbb[(size_t)jb[w][kk] * gC + lane];
            o += acc[kk] * (vv + bf2f(pebuf[w][kk][lane]));
        }
        att[(size_t)p * gC + lane] = o / s;
    }
}

// =====================================================================
// D: out2 = LN2(att @ Wo + bo) in place; accumulate channel mean. (unchanged)
// =====================================================================
__global__ __launch_bounds__(256) void k_out(
    float* __restrict__ att,
    const float* __restrict__ Wo, const float* __restrict__ bo,
    const float* __restrict__ ln2g, const float* __restrict__ ln2b,
    float* __restrict__ meanb)
{
    __shared__ __align__(16) float hb[4][64];
    int lane = threadIdx.x & 63;
    int p = blockIdx.x * 4 + (threadIdx.x >> 6);
    int b = p >> 13;
    float* hbuf = hb[threadIdx.x >> 6];
    float wo[64];
#pragma unroll
    for (int r = 0; r < 64; ++r) wo[r] = Wo[r * 64 + lane];
    float x = att[(size_t)p * gC + lane];
    hbuf[lane] = x;
    float acc = bo[lane];
#pragma unroll
    for (int q4 = 0; q4 < 16; ++q4) {
        float4 hq = *reinterpret_cast<const float4*>(&hbuf[q4 * 4]);
        acc += hq.x * wo[q4 * 4 + 0] + hq.y * wo[q4 * 4 + 1]
             + hq.z * wo[q4 * 4 + 2] + hq.w * wo[q4 * 4 + 3];
    }
    float mu = wsum(acc) * (1.f / 64);
    float d = acc - mu;
    float var = wsum(d * d) * (1.f / 64);
    float inv = 1.f / sqrtf(var + 1e-5f);
    float y = d * inv * ln2g[lane] + ln2b[lane];
    att[(size_t)p * gC + lane] = y;
    atomicAdd(&meanb[b * 64 + lane], y * (1.f / gN));
}

// =====================================================================
// F: out = LN3(out2 * cw) + features -> fp32.
// R22: k_cw fused — each wave recomputes cw from the completed meanb
// (bit-identical math to the old k_cw; ~100 instr/wave).
// =====================================================================
__global__ __launch_bounds__(256) void k_final(
    const float* __restrict__ out2, const float* __restrict__ meanb,
    const float* __restrict__ caW1, const float* __restrict__ cab1,
    const float* __restrict__ caW2, const float* __restrict__ cab2,
    const float* __restrict__ ln3g, const float* __restrict__ ln3b,
    const float* __restrict__ feat, float* __restrict__ outp)
{
    int lane = threadIdx.x & 63;
    int p = blockIdx.x * 4 + (threadIdx.x >> 6);
    int b = p >> 13;

    // ---- channel attention (was k_cw) ----
    float mv = meanb[b * 64 + lane];
    float hj = (lane < 16) ? cab1[lane] : 0.f;
    for (int cp = 0; cp < 64; ++cp) {
        float mcp = __shfl(mv, cp, 64);
        if (lane < 16) hj += mcp * caW1[cp * 16 + lane];
    }
    hj = fmaxf(hj, 0.f);
    float accw = cab2[lane];
    for (int jj = 0; jj < 16; ++jj) {
        float hv = __shfl(hj, jj, 64);
        accw += hv * caW2[jj * 64 + lane];
    }
    float cwv = 1.f / (1.f + expf(-accw));

    // ---- LN3 + residual ----
    float x = out2[(size_t)p * gC + lane] * cwv;
    float mu = wsum(x) * (1.f / 64);
    float d = x - mu;
    float var = wsum(d * d) * (1.f / 64);
    float inv = 1.f / sqrtf(var + 1e-5f);
    float y = d * inv * ln3g[lane] + ln3b[lane];
    outp[(size_t)p * gC + lane] = y + feat[(size_t)p * gC + lane];
}

// =====================================================================
extern "C" void kernel_launch(void* const* d_in, const int* in_sizes, int n_in,
                              void* d_out, int out_size, void* d_ws, size_t ws_size,
                              hipStream_t stream)
{
    (void)in_sizes; (void)n_in; (void)out_size; (void)ws_size;
    const float* xyz  = (const float*)d_in[0];
    const float* feat = (const float*)d_in[1];
    const float* ln1g = (const float*)d_in[2];
    const float* ln1b = (const float*)d_in[3];
    const float* Wq   = (const float*)d_in[4];
    const float* bq   = (const float*)d_in[5];
    const float* Wk   = (const float*)d_in[6];
    const float* bk   = (const float*)d_in[7];
    const float* Wv   = (const float*)d_in[8];
    const float* bv   = (const float*)d_in[9];
    const float* dW1  = (const float*)d_in[10];
    const float* db1  = (const float*)d_in[11];
    const float* dg   = (const float*)d_in[12];
    const float* db   = (const float*)d_in[13];
    const float* dW2  = (const float*)d_in[14];
    const float* db2  = (const float*)d_in[15];
    const float* gW1  = (const float*)d_in[16];
    const float* gb1  = (const float*)d_in[17];
    const float* gg   = (const float*)d_in[18];
    const float* gb   = (const float*)d_in[19];
    const float* gW2  = (const float*)d_in[20];
    const float* gb2  = (const float*)d_in[21];
    const float* Wo   = (const float*)d_in[22];
    const float* bo   = (const float*)d_in[23];
    const float* ln2g = (const float*)d_in[24];
    const float* ln2b = (const float*)d_in[25];
    const float* caW1 = (const float*)d_in[26];
    const float* cab1 = (const float*)d_in[27];
    const float* caW2 = (const float*)d_in[28];
    const float* cab2 = (const float*)d_in[29];
    const float* ln3g = (const float*)d_in[30];
    const float* ln3b = (const float*)d_in[31];

    const size_t BNC = (size_t)gB * gN * gC;      // 1,048,576
    float* Q    = (float*)d_ws;
    float* Kt   = Q + BNC;
    float* Vt   = Kt + BNC;
    float* att  = Vt + BNC;                        // reused in-place as out2
    int*   idx  = (int*)(att + BNC);
    float* meanb = (float*)(idx + (size_t)gB * gN * gK);
    float4* pk4  = (float4*)(meanb + 256);         // 16384 * 16 B = 256 KB

    const int PB = (gB * gN) / 4;                  // 4096 blocks

    k_lnqkv<<<PB, 256, 0, stream>>>(feat, ln1g, ln1b, Wq, bq, Wk, bk, Wv, bv,
                                    Q, Kt, Vt, meanb, xyz, pk4);
    k_knn<<<PB, 256, 0, stream>>>(pk4, idx);
    k_attn<<<PB, 256, 0, stream>>>(xyz, Q, Kt, Vt, idx,
                                   dW1, db1, dg, db, dW2, db2,
                                   gW1, gb1, gg, gb, gW2, gb2, att);
    k_out<<<PB, 256, 0, stream>>>(att, Wo, bo, ln2g, ln2b, meanb);
    k_final<<<PB, 256, 0, stream>>>(att, meanb, caW1, cab1, caW2, cab2,
                                    ln3g, ln3b, feat, (float*)d_out);
}

// Round 23
// 1062.715 us; speedup vs baseline: 1.0433x; 1.0433x over previous
//
#include <hip/hip_runtime.h>

// Problem constants (B=2, N=8192, C=64, K=32 neighbors). All device buffers fp32.
static constexpr int gB = 2;
static constexpr int gN = 8192;
static constexpr int gC = 64;
static constexpr int gK = 32;

using u16 = unsigned short;
using u32 = unsigned int;
using u64 = unsigned long long;

// wave(64)-wide sum
__device__ __forceinline__ float wsum(float v) {
#pragma unroll
    for (int m = 32; m; m >>= 1) v += __shfl_xor(v, m, 64);
    return v;
}

// bf16 pack/unpack (RNE)
__device__ __forceinline__ u16 f2bf(float f) {
    u32 u = __float_as_uint(f);
    return (u16)((u + 0x7FFFu + ((u >> 16) & 1u)) >> 16);
}
__device__ __forceinline__ float bf2f(u16 v) {
    return __uint_as_float(((u32)v) << 16);
}

// =====================================================================
// A: fn = LN1(features); Q/K/V = fn@W+b.  Wave-per-point.
// =====================================================================
__global__ __launch_bounds__(256) void k_lnqkv(
    const float* __restrict__ feat, const float* __restrict__ ln1g, const float* __restrict__ ln1b,
    const float* __restrict__ Wq, const float* __restrict__ bq,
    const float* __restrict__ Wk, const float* __restrict__ bk,
    const float* __restrict__ Wv, const float* __restrict__ bv,
    float* __restrict__ Qo, float* __restrict__ Ko, float* __restrict__ Vo,
    float* __restrict__ zero_region)
{
    if (blockIdx.x == 0) zero_region[threadIdx.x] = 0.f;   // meanb(128)+cw(128)
    int wave = threadIdx.x >> 6, lane = threadIdx.x & 63;
    int p = blockIdx.x * 4 + wave;
    float x = feat[(size_t)p * gC + lane];
    float mu = wsum(x) * (1.f / 64);
    float d = x - mu;
    float var = wsum(d * d) * (1.f / 64);
    float inv = 1.f / sqrtf(var + 1e-5f);
    float fn = d * inv * ln1g[lane] + ln1b[lane];
    float qa = bq[lane], ka = bk[lane], va = bv[lane];
    for (int cp = 0; cp < 64; ++cp) {
        float hv = __shfl(fn, cp, 64);
        qa += hv * Wq[cp * 64 + lane];
        ka += hv * Wk[cp * 64 + lane];
        va += hv * Wv[cp * 64 + lane];
    }
    size_t o = (size_t)p * gC + lane;
    Qo[o] = qa; Ko[o] = ka; Vo[o] = va;
}

// =====================================================================
// A2: pack {x,y,z,sq} per point (norm-then-square idiom).
// =====================================================================
__global__ __launch_bounds__(256) void k_pack(const float* __restrict__ xyz,
                                              float4* __restrict__ pk4)
{
#pragma clang fp contract(off)
    int p = blockIdx.x * 256 + threadIdx.x;     // 0..16383
    const float* s = xyz + (size_t)p * 3;
    float x = s[0], y = s[1], z = s[2];
    float n = sqrtf((x * x + y * y) + z * z);
    pk4[p] = make_float4(x, y, z, n * n);       // norm-then-square
}

// =====================================================================
// B: KNN top-32 — block = 4 queries (4 waves, same batch), cooperative
// LDS tile staging (8 tiles x 1024 candidates, SoA floats). Scan loop
// is pure LDS+VALU. Scoring/insert/extraction bits = passing version.
// =====================================================================
__global__ __launch_bounds__(256) void k_knn(const float4* __restrict__ pk4, int* __restrict__ idxo)
{
#pragma clang fp contract(off)
    __shared__ float xs[1024], ys[1024], zs[1024], ws[1024];   // 16 KB
    int tid = threadIdx.x;
    int wave = tid >> 6, lane = tid & 63;
    int q = blockIdx.x * 4 + wave;            // 4 queries per block, same batch
    int b = q >> 13;
    int n = q & (gN - 1);
    const float4* base = pk4 + (size_t)b * gN;
    float4 me = base[n];
    float xi = me.x, yi = me.y, zi = me.z;
    float sqi = me.w;
    u64 lst[10];
#pragma unroll
    for (int e = 0; e < 10; ++e) lst[e] = 0ull;

    for (int tile = 0; tile < 8; ++tile) {
        __syncthreads();
        // cooperative stage: 1024 float4 -> SoA (each thread 4)
#pragma unroll
        for (int t0 = 0; t0 < 4; ++t0) {
            int t = tid + (t0 << 8);
            float4 c = base[(tile << 10) + t];
            xs[t] = c.x; ys[t] = c.y; zs[t] = c.z; ws[t] = c.w;
        }
        __syncthreads();
#pragma unroll 4
        for (int i = 0; i < 16; ++i) {
            int t = (i << 6) | lane;
            int j = (tile << 10) + t;
            float inner = (xi * xs[t] + yi * ys[t]) + zi * zs[t];
            float nd = -((sqi - 2.0f * inner) + ws[t]);
            u32 u = __float_as_uint(nd);
            u32 kh = u ^ (0x80000000u | (u32)((int)u >> 31));   // order-preserving
            u64 pk = ((u64)kh << 32) | (u32)(8191 - j);          // ties -> smaller j
            if (pk > lst[9]) {
                lst[9] = pk;
#pragma unroll
                for (int e = 9; e > 0; --e) {
                    if (lst[e] > lst[e - 1]) { u64 tm = lst[e - 1]; lst[e - 1] = lst[e]; lst[e] = tm; }
                }
            }
        }
    }
    // per-wave extraction (no cross-wave deps)
    int* op = idxo + (size_t)q * gK;
    for (int r = 0; r < gK; ++r) {
        u64 g = lst[0];
#pragma unroll
        for (int m = 32; m; m >>= 1) {
            u64 o = __shfl_xor(g, m, 64);
            g = (o > g) ? o : g;
        }
        if (lst[0] == g) {                        // unique owner pops
#pragma unroll
            for (int e = 0; e < 9; ++e) lst[e] = lst[e + 1];
            lst[9] = 0ull;
        }
        if (lane == 0) op[r] = 8191 - (int)(g & 0x1FFFu);
    }
}

// =====================================================================
// C: wave-per-POINT, lane=channel, k-in-registers. (R19 structure:
// VGPR=100 no-spill, VALUBusy 71%)
// =====================================================================
__global__ __launch_bounds__(256, 2) void k_attn(
    const float* __restrict__ xyz,
    const float* __restrict__ Qb, const float* __restrict__ Kb, const float* __restrict__ Vb,
    const int* __restrict__ idxi,
    const float* __restrict__ dW1, const float* __restrict__ db1,
    const float* __restrict__ dgv, const float* __restrict__ dbv,
    const float* __restrict__ dW2, const float* __restrict__ db2,
    const float* __restrict__ gW1, const float* __restrict__ gb1,
    const float* __restrict__ ggv, const float* __restrict__ gbv,
    const float* __restrict__ gW2, const float* __restrict__ gb2,
    float* __restrict__ att)
{
    __shared__ u16 wd2s[64 * 64];          // 8 KB each: [c][swizzled cp]
    __shared__ u16 wg1s[64 * 64];
    __shared__ u16 wg2s[64 * 64];
    __shared__ float hbuf[4][32][64];      // 32 KB: per-wave activations [k][c]
    __shared__ u16 pebuf[4][32][64];       // 16 KB: per-wave pe (bf16)
    __shared__ float4 dxb[4][32];          // 2 KB
    __shared__ int jb[4][32];              // 0.5 KB

    int tid = threadIdx.x;
    int w = tid >> 6, lane = tid & 63;
    int p = blockIdx.x * 4 + w;
    int b = p >> 13;

    // ---- stage weights: bf16, transposed ([c][cp]), b64-granule swizzle ----
    for (int i = tid; i < 4096; i += 256) {
        int cp = i >> 6, c = i & 63;
        int di = c * 64 + ((((cp >> 2) ^ (c & 15)) << 2) | (cp & 3));
        wd2s[di] = f2bf(dW2[i]);
        wg1s[di] = f2bf(gW1[i]);
        wg2s[di] = f2bf(gW2[i]);
    }
    // ---- stage neighbor indices + pos diffs ----
    if (lane < 32) {
        int j = idxi[(size_t)p * gK + lane];
        jb[w][lane] = j;
        const float* xp = xyz + (size_t)p * 3;
        const float* xj = xyz + ((size_t)b * gN + j) * 3;
        dxb[w][lane] = make_float4(xp[0] - xj[0], xp[1] - xj[1], xp[2] - xj[2], 0.f);
    }
    __syncthreads();

    // per-lane (channel) parameters
    float w1x = dW1[lane], w1y = dW1[64 + lane], w1z = dW1[128 + lane], vb1 = db1[lane];
    float vdg = dgv[lane], vdb = dbv[lane];
    float vb2 = db2[lane];
    float vg1b = gb1[lane], vgg = ggv[lane], vgb = gbv[lane], vg2b = gb2[lane];
    float q = Qb[(size_t)p * gC + lane];

    // ---- fc_delta layer 1 + LN + relu -> hbuf ----
#pragma unroll
    for (int kk = 0; kk < 32; ++kk) {
        float4 d4 = dxb[w][kk];
        float t = d4.x * w1x + d4.y * w1y + d4.z * w1z + vb1;
        float mu = wsum(t) * (1.f / 64);
        float td = t - mu;
        float var = wsum(td * td) * (1.f / 64);
        float inv = 1.f / sqrtf(var + 1e-5f);
        hbuf[w][kk][lane] = fmaxf(td * inv * vdg + vdb, 0.f);
    }

    float acc[32];

    // ---- fc_delta layer 2: pe = h @ dW2 + db2 ----
#pragma unroll
    for (int kk = 0; kk < 32; ++kk) acc[kk] = vb2;
    for (int cp4 = 0; cp4 < 16; ++cp4) {
        int pg = cp4 ^ (lane & 15);
        uint2 wp = *reinterpret_cast<const uint2*>(&wd2s[lane * 64 + pg * 4]);
        float w0 = bf2f((u16)(wp.x & 0xFFFFu)), w1 = bf2f((u16)(wp.x >> 16));
        float w2 = bf2f((u16)(wp.y & 0xFFFFu)), w3 = bf2f((u16)(wp.y >> 16));
#pragma unroll
        for (int kk = 0; kk < 32; ++kk) {
            float4 h4 = *reinterpret_cast<const float4*>(&hbuf[w][kk][cp4 * 4]);
            acc[kk] += h4.x * w0 + h4.y * w1 + h4.z * w2 + h4.w * w3;
        }
    }
#pragma unroll
    for (int kk = 0; kk < 32; ++kk) pebuf[w][kk][lane] = f2bf(acc[kk]);

    // ---- attn_in = (q - k) + pe -> hbuf ----
    {
        const float* Kbb = Kb + (size_t)b * gN * gC;
#pragma unroll
        for (int kk = 0; kk < 32; ++kk) {
            float kv = Kbb[(size_t)jb[w][kk] * gC + lane];
            hbuf[w][kk][lane] = (q - kv) + acc[kk];
        }
    }

    // ---- fc_gamma layer 1 ----
#pragma unroll
    for (int kk = 0; kk < 32; ++kk) acc[kk] = vg1b;
    for (int cp4 = 0; cp4 < 16; ++cp4) {
        int pg = cp4 ^ (lane & 15);
        uint2 wp = *reinterpret_cast<const uint2*>(&wg1s[lane * 64 + pg * 4]);
        float w0 = bf2f((u16)(wp.x & 0xFFFFu)), w1 = bf2f((u16)(wp.x >> 16));
        float w2 = bf2f((u16)(wp.y & 0xFFFFu)), w3 = bf2f((u16)(wp.y >> 16));
#pragma unroll
        for (int kk = 0; kk < 32; ++kk) {
            float4 h4 = *reinterpret_cast<const float4*>(&hbuf[w][kk][cp4 * 4]);
            acc[kk] += h4.x * w0 + h4.y * w1 + h4.z * w2 + h4.w * w3;
        }
    }
    // ---- LN + relu -> hbuf ----
#pragma unroll
    for (int kk = 0; kk < 32; ++kk) {
        float a = acc[kk];
        float mu = wsum(a) * (1.f / 64);
        float ad = a - mu;
        float var = wsum(ad * ad) * (1.f / 64);
        float inv = 1.f / sqrtf(var + 1e-5f);
        hbuf[w][kk][lane] = fmaxf(ad * inv * vgg + vgb, 0.f);
    }

    // ---- fc_gamma layer 2 -> logits ----
#pragma unroll
    for (int kk = 0; kk < 32; ++kk) acc[kk] = vg2b;
    for (int cp4 = 0; cp4 < 16; ++cp4) {
        int pg = cp4 ^ (lane & 15);
        uint2 wp = *reinterpret_cast<const uint2*>(&wg2s[lane * 64 + pg * 4]);
        float w0 = bf2f((u16)(wp.x & 0xFFFFu)), w1 = bf2f((u16)(wp.x >> 16));
        float w2 = bf2f((u16)(wp.y & 0xFFFFu)), w3 = bf2f((u16)(wp.y >> 16));
#pragma unroll
        for (int kk = 0; kk < 32; ++kk) {
            float4 h4 = *reinterpret_cast<const float4*>(&hbuf[w][kk][cp4 * 4]);
            acc[kk] += h4.x * w0 + h4.y * w1 + h4.z * w2 + h4.w * w3;
        }
    }

    // ---- softmax over k (in-lane) + out = sum a*(v+pe) ----
#pragma unroll
    for (int kk = 0; kk < 32; ++kk) acc[kk] *= 0.3535533905932738f;   // /sqrt(8)
    float mx = acc[0];
#pragma unroll
    for (int kk = 1; kk < 32; ++kk) mx = fmaxf(mx, acc[kk]);
    float s = 0.f;
#pragma unroll
    for (int kk = 0; kk < 32; ++kk) { acc[kk] = expf(acc[kk] - mx); s += acc[kk]; }
    {
        const float* Vbb = Vb + (size_t)b * gN * gC;
        float o = 0.f;
#pragma unroll
        for (int kk = 0; kk < 32; ++kk) {
            float vv = Vbb[(size_t)jb[w][kk] * gC + lane];
            o += acc[kk] * (vv + bf2f(pebuf[w][kk][lane]));
        }
        att[(size_t)p * gC + lane] = o / s;
    }
}

// =====================================================================
// D: out2 = LN2(att @ Wo + bo) in place; accumulate channel mean.
// =====================================================================
__global__ __launch_bounds__(256) void k_out(
    float* __restrict__ att,
    const float* __restrict__ Wo, const float* __restrict__ bo,
    const float* __restrict__ ln2g, const float* __restrict__ ln2b,
    float* __restrict__ meanb)
{
    __shared__ __align__(16) float hb[4][64];
    int lane = threadIdx.x & 63;
    int p = blockIdx.x * 4 + (threadIdx.x >> 6);
    int b = p >> 13;
    float* hbuf = hb[threadIdx.x >> 6];
    float wo[64];
#pragma unroll
    for (int r = 0; r < 64; ++r) wo[r] = Wo[r * 64 + lane];
    float x = att[(size_t)p * gC + lane];
    hbuf[lane] = x;
    float acc = bo[lane];
#pragma unroll
    for (int q4 = 0; q4 < 16; ++q4) {
        float4 hq = *reinterpret_cast<const float4*>(&hbuf[q4 * 4]);
        acc += hq.x * wo[q4 * 4 + 0] + hq.y * wo[q4 * 4 + 1]
             + hq.z * wo[q4 * 4 + 2] + hq.w * wo[q4 * 4 + 3];
    }
    float mu = wsum(acc) * (1.f / 64);
    float d = acc - mu;
    float var = wsum(d * d) * (1.f / 64);
    float inv = 1.f / sqrtf(var + 1e-5f);
    float y = d * inv * ln2g[lane] + ln2b[lane];
    att[(size_t)p * gC + lane] = y;
    atomicAdd(&meanb[b * 64 + lane], y * (1.f / gN));
}

// =====================================================================
// E: cw = sigmoid(relu(mean @ ca_W1 + ca_b1) @ ca_W2 + ca_b2)
// =====================================================================
__global__ void k_cw(const float* __restrict__ meanb,
                     const float* __restrict__ caW1, const float* __restrict__ cab1,
                     const float* __restrict__ caW2, const float* __restrict__ cab2,
                     float* __restrict__ cw)
{
    int b = blockIdx.x, lane = threadIdx.x;    // 64 threads
    float mv = meanb[b * 64 + lane];
    float hj = (lane < 16) ? cab1[lane] : 0.f;
    for (int cp = 0; cp < 64; ++cp) {
        float mcp = __shfl(mv, cp, 64);
        if (lane < 16) hj += mcp * caW1[cp * 16 + lane];
    }
    hj = fmaxf(hj, 0.f);
    float acc = cab2[lane];
    for (int jj = 0; jj < 16; ++jj) {
        float hv = __shfl(hj, jj, 64);
        acc += hv * caW2[jj * 64 + lane];
    }
    cw[b * 64 + lane] = 1.f / (1.f + expf(-acc));
}

// =====================================================================
// F: out = LN3(out2 * cw) + features  -> fp32
// =====================================================================
__global__ __launch_bounds__(256) void k_final(
    const float* __restrict__ out2, const float* __restrict__ cw,
    const float* __restrict__ ln3g, const float* __restrict__ ln3b,
    const float* __restrict__ feat, float* __restrict__ outp)
{
    int lane = threadIdx.x & 63;
    int p = blockIdx.x * 4 + (threadIdx.x >> 6);
    int b = p >> 13;
    float x = out2[(size_t)p * gC + lane] * cw[b * 64 + lane];
    float mu = wsum(x) * (1.f / 64);
    float d = x - mu;
    float var = wsum(d * d) * (1.f / 64);
    float inv = 1.f / sqrtf(var + 1e-5f);
    float y = d * inv * ln3g[lane] + ln3b[lane];
    outp[(size_t)p * gC + lane] = y + feat[(size_t)p * gC + lane];
}

// =====================================================================
extern "C" void kernel_launch(void* const* d_in, const int* in_sizes, int n_in,
                              void* d_out, int out_size, void* d_ws, size_t ws_size,
                              hipStream_t stream)
{
    (void)in_sizes; (void)n_in; (void)out_size; (void)ws_size;
    const float* xyz  = (const float*)d_in[0];
    const float* feat = (const float*)d_in[1];
    const float* ln1g = (const float*)d_in[2];
    const float* ln1b = (const float*)d_in[3];
    const float* Wq   = (const float*)d_in[4];
    const float* bq   = (const float*)d_in[5];
    const float* Wk   = (const float*)d_in[6];
    const float* bk   = (const float*)d_in[7];
    const float* Wv   = (const float*)d_in[8];
    const float* bv   = (const float*)d_in[9];
    const float* dW1  = (const float*)d_in[10];
    const float* db1  = (const float*)d_in[11];
    const float* dg   = (const float*)d_in[12];
    const float* db   = (const float*)d_in[13];
    const float* dW2  = (const float*)d_in[14];
    const float* db2  = (const float*)d_in[15];
    const float* gW1  = (const float*)d_in[16];
    const float* gb1  = (const float*)d_in[17];
    const float* gg   = (const float*)d_in[18];
    const float* gb   = (const float*)d_in[19];
    const float* gW2  = (const float*)d_in[20];
    const float* gb2  = (const float*)d_in[21];
    const float* Wo   = (const float*)d_in[22];
    const float* bo   = (const float*)d_in[23];
    const float* ln2g = (const float*)d_in[24];
    const float* ln2b = (const float*)d_in[25];
    const float* caW1 = (const float*)d_in[26];
    const float* cab1 = (const float*)d_in[27];
    const float* caW2 = (const float*)d_in[28];
    const float* cab2 = (const float*)d_in[29];
    const float* ln3g = (const float*)d_in[30];
    const float* ln3b = (const float*)d_in[31];

    const size_t BNC = (size_t)gB * gN * gC;      // 1,048,576
    float* Q    = (float*)d_ws;
    float* Kt   = Q + BNC;
    float* Vt   = Kt + BNC;
    float* att  = Vt + BNC;                        // reused in-place as out2
    int*   idx  = (int*)(att + BNC);
    float* meanb = (float*)(idx + (size_t)gB * gN * gK);
    float* cw    = meanb + 128;
    float4* pk4  = (float4*)(cw + 128);            // 16384 * 16 B = 256 KB

    const int PB = (gB * gN) / 4;                  // 4096 blocks

    k_lnqkv<<<PB, 256, 0, stream>>>(feat, ln1g, ln1b, Wq, bq, Wk, bk, Wv, bv, Q, Kt, Vt, meanb);
    k_pack<<<(gB * gN) / 256, 256, 0, stream>>>(xyz, pk4);
    k_knn<<<PB, 256, 0, stream>>>(pk4, idx);
    k_attn<<<PB, 256, 0, stream>>>(xyz, Q, Kt, Vt, idx,
                                   dW1, db1, dg, db, dW2, db2,
                                   gW1, gb1, gg, gb, gW2, gb2, att);
    k_out<<<PB, 256, 0, stream>>>(att, Wo, bo, ln2g, ln2b, meanb);
    k_cw<<<gB, 64, 0, stream>>>(meanb, caW1, cab1, caW2, cab2, cw);
    k_final<<<PB, 256, 0, stream>>>(att, cw, ln3g, ln3b, feat, (float*)d_out);
}